// Round 10
// baseline (295.835 us; speedup 1.0000x reference)
//
#include <hip/hip_runtime.h>
#include <hip/hip_bf16.h>
#include <stdint.h>

#define N 4096
#define BM 128     // sym tile (triangular 528-block grid)
#define SK 128     // fp8 K-tile
// gemm_pv 8-phase geometry:
#define PM 256
#define PN 256
#define PK 64

typedef __hip_bfloat16 bf16;
typedef __attribute__((ext_vector_type(8))) __bf16 bfrag;   // 8 bf16 (MFMA A/B operand)
typedef __attribute__((ext_vector_type(4))) float floatx4;  // MFMA C/D operand
typedef __attribute__((ext_vector_type(8))) int i32x8;      // 32 fp8 (f8f6f4 A/B operand)
typedef __attribute__((ext_vector_type(4))) int i32x4;

// ---------------------------------------------------------------------------
// async global -> LDS, 16B per lane (global_load_lds_dwordx4)
// ---------------------------------------------------------------------------
__device__ __forceinline__ void gld_lds16(const void* g, void* l) {
    __builtin_amdgcn_global_load_lds(
        (const __attribute__((address_space(1))) void*)g,
        (__attribute__((address_space(3))) void*)l, 16, 0, 0);
}

__device__ __forceinline__ unsigned short f2bf(float x) {
    __hip_bfloat16 h = __float2bfloat16(x);
    return *(unsigned short*)&h;
}

#define PV_BAR()   __builtin_amdgcn_s_barrier()
#define PV_LGKM0() asm volatile("s_waitcnt lgkmcnt(0)" ::: "memory")
#define PV_VM4()   asm volatile("s_waitcnt vmcnt(4)" ::: "memory")

// ---------------------------------------------------------------------------
// Kernel 1: xb = bf16(in * 1/64)  (scaled, for gemm_pv's B operand)
//           x8 = fp8_e4m3(in)     (UNSCALED -- the 1/4096 is applied exactly
//                                  via the MFMA e8m0 scale operands)
// rowsum zeroing via hipMemsetAsync (stream-ordered).
// ---------------------------------------------------------------------------
__global__ __launch_bounds__(256) void cvt_scale(const float* __restrict__ in,
                                                 unsigned short* __restrict__ xb,
                                                 uint8_t* __restrict__ x8) {
    const long i = ((long)blockIdx.x * 256 + threadIdx.x) * 8;
    float4 a = *(const float4*)(in + i);
    float4 b = *(const float4*)(in + i + 4);
    const float sc = 0.015625f;  // 1/64 = 1/sqrt(4096)
    float v[8] = {a.x, a.y, a.z, a.w, b.x, b.y, b.z, b.w};
    alignas(16) unsigned short r[8];
#pragma unroll
    for (int k = 0; k < 8; ++k) r[k] = f2bf(v[k] * sc);
    *(uint4*)(xb + i) = *(const uint4*)r;

    int p0 = __builtin_amdgcn_cvt_pk_fp8_f32(v[0], v[1], 0, false);
    p0     = __builtin_amdgcn_cvt_pk_fp8_f32(v[2], v[3], p0, true);
    int p1 = __builtin_amdgcn_cvt_pk_fp8_f32(v[4], v[5], 0, false);
    p1     = __builtin_amdgcn_cvt_pk_fp8_f32(v[6], v[7], p1, true);
    int2 pk; pk.x = p0; pk.y = p1;
    *(int2*)(x8 + i) = pk;
}

// ---------------------------------------------------------------------------
// Kernel 2 (gemm_sym): E = exp(mask(x x^T)), triangular 528-block grid of
// 128^2 tiles, 256 threads / 4 waves (2x2), 64x64 wave tile, fp8 K=128 via
// mfma_scale_f32_16x16x128_f8f6f4 (e8m0 2^-6 scales -> exact 1/4096).
// R10 (vs R7's 2-phase + syncthreads, which still DRAINED vmcnt(0) every
// iteration -- the T4 anti-pattern): depth-2 counted-vmcnt pipeline.
//   - TRIPLE-buffered LDS (3 x 32 KB = 96 KB, 1 block/CU)
//   - stage tile kt+2 each iter into buf (kt+2)%3
//   - iter end: s_waitcnt vmcnt(8) (leaves exactly T(kt+2)'s 8 loads in
//     flight across the raw s_barrier -> T(kt+1) landed, m135 in-order
//     vmcnt) -- never drains in-loop; kt>=30 uses vmcnt(0) so the epilogue
//     LDS reuse is race-free.
// Everything else (sigma-swizzle, fragment reads at slots q^l7/(4+q)^l7,
// MFMA, epilogue, XCD-chunk swizzle 528=8x66) byte-identical to R7.
// ---------------------------------------------------------------------------
__global__ __launch_bounds__(256) void gemm_sym(const uint8_t* __restrict__ X8,
                                                unsigned short* __restrict__ E,
                                                float* __restrict__ rowsum) {
    __shared__ __align__(16) uint8_t smem[98304];  // 3 x (A 16KB + B 16KB)

    const int t    = threadIdx.x;
    const int lane = t & 63;
    const int wave = t >> 6;      // 0..3
    const int wm   = wave >> 1;   // 0..1  (64-row strip)
    const int wn   = wave & 1;    // 0..1  (64-col strip)
    const int l15  = lane & 15;
    const int l7   = lane & 7;
    const int q    = lane >> 4;

    // XCD-chunk swizzle: XCD x owns the contiguous triangle range [66x,66x+65]
    const int b0 = blockIdx.x;
    const int b  = (b0 & 7) * 66 + (b0 >> 3);
    // decode triangular block index: b = I*(I+1)/2 + J, J <= I  (32 rows)
    int I = (int)((sqrtf((float)(8 * b + 1)) - 1.0f) * 0.5f);
    if ((I + 1) * (I + 2) / 2 <= b) ++I;   // fp-safety fixups
    if (I * (I + 1) / 2 > b) --I;
    const int Jb = b - I * (I + 1) / 2;
    const int bm = I * BM;   // row block (>= col block)
    const int bn = Jb * BM;
    const bool diag = (I == Jb);

    floatx4 acc[4][4] = {};

    // staging: slot s=t covers row srow (32 rows/issue), slot t&7 holds
    // global k-block sigma^-1((t&7)^(srow&7)); fragment reads then hit
    // slots q^l7 / (4+q)^l7 (0-conflict pattern, verified R4-R9)
    const int srow = t >> 3;                    // 0..31 (+32*i)
    const int x_   = (t & 7) ^ (srow & 7);
    const int skb  = ((x_ & 3) << 1) | (x_ >> 2);   // sigma^-1
    const uint8_t* Ag = X8 + (long)(bm + srow) * N + skb * 16;
    const uint8_t* Bg = X8 + (long)(bn + srow) * N + skb * 16;

    // prologue: stage T0 -> buf0 (8 loads), T1 -> buf1 (8 loads);
    // vmcnt(8) -> T0 landed (per wave), barrier publishes to all waves.
#pragma unroll
    for (int i = 0; i < 4; ++i) {
        gld_lds16(Ag + (long)i * 32 * N, smem + t * 16 + i * 4096);
        gld_lds16(Bg + (long)i * 32 * N, smem + 16384 + t * 16 + i * 4096);
    }
#pragma unroll
    for (int i = 0; i < 4; ++i) {
        gld_lds16(Ag + (long)i * 32 * N + SK, smem + 32768 + t * 16 + i * 4096);
        gld_lds16(Bg + (long)i * 32 * N + SK, smem + 32768 + 16384 + t * 16 + i * 4096);
    }
    asm volatile("s_waitcnt vmcnt(8)" ::: "memory");
    PV_BAR();

    int cur = 0;
    for (int kt = 0; kt < 32; ++kt) {
        // stage tile kt+2 into buf (cur+2)%3 (8 loads; stays in flight
        // across this iter's barrier -- consumed two iters from now)
        if (kt < 30) {
            int pb = cur + 2; if (pb >= 3) pb -= 3;
            const int kp = (kt + 2) * SK;
            uint8_t* An = smem + pb * 32768 + t * 16;
#pragma unroll
            for (int i = 0; i < 4; ++i) {
                gld_lds16(Ag + (long)i * 32 * N + kp, An + i * 4096);
                gld_lds16(Bg + (long)i * 32 * N + kp, An + 16384 + i * 4096);
            }
        }

        const uint8_t* As = smem + cur * 32768;
        const uint8_t* Bs = As + 16384;
        i32x8 af[4], bfr[4];
#pragma unroll
        for (int i = 0; i < 4; ++i) {
            const int row = wm * 64 + i * 16 + l15;   // row&7 == l7
            i32x4 lo = *(const i32x4*)&As[(row * 8 + (q ^ l7)) * 16];
            i32x4 hi = *(const i32x4*)&As[(row * 8 + ((4 + q) ^ l7)) * 16];
            af[i] = (i32x8){lo.x, lo.y, lo.z, lo.w, hi.x, hi.y, hi.z, hi.w};
        }
#pragma unroll
        for (int j = 0; j < 4; ++j) {
            const int row = wn * 64 + j * 16 + l15;
            i32x4 lo = *(const i32x4*)&Bs[(row * 8 + (q ^ l7)) * 16];
            i32x4 hi = *(const i32x4*)&Bs[(row * 8 + ((4 + q) ^ l7)) * 16];
            bfr[j] = (i32x8){lo.x, lo.y, lo.z, lo.w, hi.x, hi.y, hi.z, hi.w};
        }
#pragma unroll
        for (int i = 0; i < 4; ++i)
#pragma unroll
            for (int j = 0; j < 4; ++j)
                acc[i][j] = __builtin_amdgcn_mfma_scale_f32_16x16x128_f8f6f4(
                    af[i], bfr[j], acc[i][j],
                    0, 0,               // cbsz (A fp8 e4m3), blgp (B fp8)
                    0, 0x79797979,      // A scale: e8m0 121 = 2^-6
                    0, 0x79797979);     // B scale: 2^-6  (product: 1/4096)

        // counted wait: leave only T(kt+2)'s 8 loads in flight -> T(kt+1)
        // landed (mine); barrier -> landed for ALL waves.  Tail: drain.
        if (kt < 30) { asm volatile("s_waitcnt vmcnt(8)" ::: "memory"); }
        else         { asm volatile("s_waitcnt vmcnt(0)" ::: "memory"); }
        PV_BAR();
        cur = (cur == 2) ? 0 : cur + 1;
    }

    // ---- epilogue: C/D layout col=lane&15, row=(lane>>4)*4+reg ----
    const int col0 = bn + wn * 64 + l15;
    const int row0 = bm + wm * 64 + q * 4;

#pragma unroll
    for (int i = 0; i < 4; ++i) {
#pragma unroll
        for (int r = 0; r < 4; ++r) {
            const int row = row0 + i * 16 + r;
            float rs = 0.f;
#pragma unroll
            for (int j = 0; j < 4; ++j) {
                const int col = col0 + j * 16;
                // no max-subtraction: sims ~ +-0.3, exp safe; shift cancels.
                float e = (row == col) ? 0.f : __expf(acc[i][j][r]);
                acc[i][j][r] = e;
                rs += e;
                E[(long)row * N + col] = f2bf(e);
            }
#pragma unroll
            for (int off = 1; off < 16; off <<= 1) rs += __shfl_xor(rs, off);
            if (l15 == 0) atomicAdd(rowsum + row, rs);
        }
    }

    if (!diag) {
        // column sums -> row sums of the mirror tile
#pragma unroll
        for (int j = 0; j < 4; ++j) {
            float cs = 0.f;
#pragma unroll
            for (int i = 0; i < 4; ++i)
#pragma unroll
                for (int r = 0; r < 4; ++r) cs += acc[i][j][r];
            cs += __shfl_xor(cs, 16);
            cs += __shfl_xor(cs, 32);
            if (q == 0) atomicAdd(rowsum + bn + wn * 64 + j * 16 + l15, cs);
        }

        // per-wave 64x64 transpose through swizzled LDS (8 KB/wave; the
        // K-loop tail used vmcnt(0), so no staging loads are in flight)
        unsigned short* tb = (unsigned short*)smem + wave * 4096;
        __syncthreads();
#pragma unroll
        for (int i = 0; i < 4; ++i) {
            const int lr0 = i * 16 + q * 4;
            const int blk = lr0 >> 3;
            const int half = (lr0 >> 2) & 1;
#pragma unroll
            for (int j = 0; j < 4; ++j) {
                const int lc = j * 16 + l15;
                union { unsigned short u[4]; uint2 v2; } pk;
#pragma unroll
                for (int r = 0; r < 4; ++r) pk.u[r] = f2bf(acc[i][j][r]);
                *(uint2*)&tb[lc * 64 + 8 * (blk ^ (lc & 7)) + 4 * half] = pk.v2;
            }
        }
        __syncthreads();

        const int gr0 = lane >> 3;
        const int cb  = lane & 7;
#pragma unroll
        for (int p = 0; p < 8; ++p) {
            const int gr = p * 8 + gr0;
            uint4 v = *(const uint4*)&tb[gr * 64 + 8 * (cb ^ (gr & 7))];
            *(uint4*)&E[(long)(bn + wn * 64 + gr) * N + bm + wm * 64 + cb * 8] = v;
        }
    }
}

// ---------------------------------------------------------------------------
// Kernel 3 (gemm_pv): out = (E/rowsum) x^T.  256^2 8-phase schedule
// (T3+T4 counted-vmcnt + T5 setprio) -- R7/R9-verified (118.5-119.0 us /
// ~1160 TF / MfmaUtil 49% / 0 conflicts).  UNCHANGED.
// ---------------------------------------------------------------------------
#define PV_STAGE_A(buf, h, k0) do { \
    const bf16* s_ = Asrc + (h) * 128 * (long)N + (k0); \
    bf16* d_ = dstl + (buf) * 16384 + (h) * 8192; \
    gld_lds16(s_, d_); \
    gld_lds16(s_ + 64 * (long)N, d_ + 4096); } while (0)

#define PV_STAGE_B(buf, h, k0) do { \
    const bf16* s_ = Bsrc + (h) * 128 * (long)N + (k0); \
    bf16* d_ = dstl + 32768 + (buf) * 16384 + (h) * 8192; \
    gld_lds16(s_, d_); \
    gld_lds16(s_ + 64 * (long)N, d_ + 4096); } while (0)

#define PV_LDA(buf, mi) do { \
    const bf16* b_ = lds + (buf) * 16384; \
    _Pragma("unroll") for (int f_ = 0; f_ < 4; ++f_) { \
      const int r_ = wm * 128 + (mi) * 64 + f_ * 16 + l15; \
      ar[f_][0] = *(const bfrag*)&b_[(r_ * 8 + (q ^ l7)) * 8]; \
      ar[f_][1] = *(const bfrag*)&b_[(r_ * 8 + ((4 + q) ^ l7)) * 8]; } } while (0)

#define PV_LDB(buf, nj) do { \
    const bf16* b_ = lds + 32768 + (buf) * 16384; \
    _Pragma("unroll") for (int g_ = 0; g_ < 2; ++g_) { \
      const int r_ = wn * 64 + (nj) * 32 + g_ * 16 + l15; \
      br[nj][g_][0] = *(const bfrag*)&b_[(r_ * 8 + (q ^ l7)) * 8]; \
      br[nj][g_][1] = *(const bfrag*)&b_[(r_ * 8 + ((4 + q) ^ l7)) * 8]; } } while (0)

#define PV_MM(mi, nj) do { \
    __builtin_amdgcn_s_setprio(1); \
    _Pragma("unroll") for (int f_ = 0; f_ < 4; ++f_) \
    _Pragma("unroll") for (int g_ = 0; g_ < 2; ++g_) \
    _Pragma("unroll") for (int k_ = 0; k_ < 2; ++k_) \
      acc[(mi)*4+f_][(nj)*2+g_] = __builtin_amdgcn_mfma_f32_16x16x32_bf16( \
          ar[f_][k_], br[nj][g_][k_], acc[(mi)*4+f_][(nj)*2+g_], 0, 0, 0); \
    __builtin_amdgcn_s_setprio(0); } while (0)

__global__ __launch_bounds__(512, 2) void gemm_pv(const bf16* __restrict__ A,
                                                  const bf16* __restrict__ B,
                                                  float* __restrict__ C,
                                                  const float* __restrict__ rowsum) {
    __shared__ __align__(16) bf16 lds[4 * 16384];  // 128 KiB: A0 A1 B0 B1

    const int t    = threadIdx.x;
    const int lane = t & 63;
    const int wm   = (t >> 6) >> 2;  // 0..1 (128-row strip)
    const int wn   = (t >> 6) & 3;   // 0..3 (64-col strip)
    const int l15  = lane & 15;
    const int l7   = lane & 7;
    const int q    = lane >> 4;

    // bijective XCD swizzle (256 blocks % 8 XCDs == 0)
    const int swz = (blockIdx.x & 7) * 32 + (blockIdx.x >> 3);
    const int bm  = (swz >> 4) * PM;
    const int bn  = (swz & 15) * PN;

    const int srow = t >> 3;
    const int skb  = (t & 7) ^ (srow & 7);
    const bf16* Asrc = A + (long)(bm + srow) * N + skb * 8;
    const bf16* Bsrc = B + (long)(bn + srow) * N + skb * 8;
    bf16* dstl = lds + t * 8;

    floatx4 acc[8][4] = {};
    bfrag ar[4][2], br[2][2][2];

    // prologue: B(0),A(0) -> buf0; B(1) -> buf1.  A(1) staged in ph1/2.
    PV_STAGE_B(0, 0, 0); PV_STAGE_B(0, 1, 0);
    PV_STAGE_A(0, 0, 0); PV_STAGE_A(0, 1, 0);
    PV_STAGE_B(1, 0, PK); PV_STAGE_B(1, 1, PK);
    PV_VM4();
    PV_BAR();

    for (int i = 0; i < 32; ++i) {
        const int ka1 = ((2 * i + 1) * PK) & (N - 1);
        const int kb2 = ((2 * i + 2) * PK) & (N - 1);
        const int kb3 = ((2 * i + 3) * PK) & (N - 1);
        PV_LDA(0, 0); PV_LDB(0, 0); PV_STAGE_A(1, 0, ka1);
        PV_BAR(); PV_LGKM0();
        PV_MM(0, 0);
        PV_BAR();
        PV_LDB(0, 1); PV_STAGE_A(1, 1, ka1);
        PV_BAR(); PV_LGKM0();
        PV_MM(0, 1);
        PV_BAR();
        PV_LDA(0, 1); PV_STAGE_B(0, 0, kb2);
        PV_BAR(); PV_LGKM0();
        PV_MM(1, 1);
        PV_BAR();
        PV_STAGE_B(0, 1, kb2);
        PV_BAR();
        PV_MM(1, 0);
        PV_VM4(); PV_BAR();
        PV_LDA(1, 0); PV_LDB(1, 0); PV_STAGE_A(0, 0, kb2);
        PV_BAR(); PV_LGKM0();
        PV_MM(0, 0);
        PV_BAR();
        PV_LDB(1, 1); PV_STAGE_A(0, 1, kb2);
        PV_BAR(); PV_LGKM0();
        PV_MM(0, 1);
        PV_BAR();
        PV_LDA(1, 1); PV_STAGE_B(1, 0, kb3);
        PV_BAR(); PV_LGKM0();
        PV_MM(1, 1);
        PV_BAR();
        PV_STAGE_B(1, 1, kb3);
        PV_BAR();
        PV_MM(1, 0);
        PV_VM4(); PV_BAR();
    }

    // epilogue: C/D layout col=lane&15, row=q*4+reg; fuse 1/rowsum
    const int rowbase = bm + wm * 128 + q * 4;
    const int colbase = bn + wn * 64 + l15;
#pragma unroll
    for (int f = 0; f < 8; ++f) {
#pragma unroll
        for (int r = 0; r < 4; ++r) {
            const int row = rowbase + f * 16 + r;
            const float inv = 1.0f / rowsum[row];
#pragma unroll
            for (int g = 0; g < 4; ++g)
                C[(long)row * N + colbase + g * 16] = acc[f][g][r] * inv;
        }
    }
}

// ---------------------------------------------------------------------------
extern "C" void kernel_launch(void* const* d_in, const int* in_sizes, int n_in,
                              void* d_out, int out_size, void* d_ws, size_t ws_size,
                              hipStream_t stream) {
    const float* in = (const float*)d_in[0];
    float* out = (float*)d_out;

    // ws layout: [rowsum 16KB] [xb 32MB bf16] [E 32MB bf16].
    // x8 (16MB fp8) lives in d_out's first 16MB -- dead until gemm_pv's
    // final write, which happens after gemm_sym has consumed x8.
    float* rowsum = (float*)d_ws;
    bf16* xb = (bf16*)((char*)d_ws + 16384);
    unsigned short* E = (unsigned short*)((char*)d_ws + 16384 + (size_t)N * N * sizeof(bf16));
    uint8_t* x8 = (uint8_t*)d_out;

    hipMemsetAsync(rowsum, 0, 16384, stream);   // stream-ordered zeroing

    cvt_scale<<<(N * (long)N) / (256 * 8), 256, 0, stream>>>(
        in, (unsigned short*)xb, x8);

    // E = exp(mask(x x^T)) via 528 triangular 128^2 fp8 tiles
    // (depth-2 counted-vmcnt tri-buffer pipeline + XCD-chunk swizzle)
    gemm_sym<<<528, 256, 0, stream>>>(x8, E, rowsum);
    // out = (E / rowsum) x^T  -- 256^2 8-phase, 256 blocks (1/CU)
    gemm_pv<<<256, 512, 0, stream>>>((const bf16*)E, xb, out, rowsum);
}

// Round 11
// 277.919 us; speedup vs baseline: 1.0645x; 1.0645x over previous
//
#include <hip/hip_runtime.h>
#include <hip/hip_bf16.h>
#include <stdint.h>

#define N 4096
#define BM 128     // sym tile (triangular 528-block grid)
#define SK 128     // fp8 K-tile
// gemm_pv 8-phase geometry:
#define PM 256
#define PN 256
#define PK 64

typedef __hip_bfloat16 bf16;
typedef __attribute__((ext_vector_type(8))) __bf16 bfrag;   // 8 bf16 (MFMA A/B operand)
typedef __attribute__((ext_vector_type(4))) float floatx4;  // MFMA C/D operand
typedef __attribute__((ext_vector_type(8))) int i32x8;      // 32 fp8 (f8f6f4 A/B operand)
typedef __attribute__((ext_vector_type(4))) int i32x4;

// ---------------------------------------------------------------------------
// async global -> LDS, 16B per lane (global_load_lds_dwordx4)
// ---------------------------------------------------------------------------
__device__ __forceinline__ void gld_lds16(const void* g, void* l) {
    __builtin_amdgcn_global_load_lds(
        (const __attribute__((address_space(1))) void*)g,
        (__attribute__((address_space(3))) void*)l, 16, 0, 0);
}

__device__ __forceinline__ unsigned short f2bf(float x) {
    __hip_bfloat16 h = __float2bfloat16(x);
    return *(unsigned short*)&h;
}

#define PV_BAR()   __builtin_amdgcn_s_barrier()
#define PV_LGKM0() asm volatile("s_waitcnt lgkmcnt(0)" ::: "memory")
#define PV_VM4()   asm volatile("s_waitcnt vmcnt(4)" ::: "memory")

// ---------------------------------------------------------------------------
// Kernel 1: xb = bf16(in * 1/64)  (scaled, for gemm_pv's B operand)
//           x8 = fp8_e4m3(in)     (UNSCALED -- the 1/4096 is applied exactly
//                                  via the MFMA e8m0 scale operands)
// R11: UNIT-STRIDE coalescing.  The old layout gave each lane 32 contiguous
// bytes (two float4 at lane-stride 32B) -- every load/store instruction
// covered a 2KB span at half density.  Now lane l handles floats
// [wbase + 4l] and [wbase + 256 + 4l]: loads are 16B/lane unit-stride
// (the guide's ideal), xb stores 8B/lane, x8 stores 4B/lane -- all
// contiguous per instruction.  Same FLOPs, same grid (8192 blocks).
// ---------------------------------------------------------------------------
__global__ __launch_bounds__(256) void cvt_scale(const float* __restrict__ in,
                                                 unsigned short* __restrict__ xb,
                                                 uint8_t* __restrict__ x8) {
    const int lane = threadIdx.x & 63;
    // wave's first float index: block covers 2048 floats, wave covers 512
    const long wbase = (long)blockIdx.x * 2048 + (threadIdx.x >> 6) * 512;
    const long ia = wbase + lane * 4;        // first 1KB of the wave
    const long ib = wbase + 256 + lane * 4;  // second 1KB

    float4 a = *(const float4*)(in + ia);
    float4 b = *(const float4*)(in + ib);
    const float sc = 0.015625f;  // 1/64 = 1/sqrt(4096)

    alignas(8) unsigned short ra[4], rb[4];
    ra[0] = f2bf(a.x * sc); ra[1] = f2bf(a.y * sc);
    ra[2] = f2bf(a.z * sc); ra[3] = f2bf(a.w * sc);
    rb[0] = f2bf(b.x * sc); rb[1] = f2bf(b.y * sc);
    rb[2] = f2bf(b.z * sc); rb[3] = f2bf(b.w * sc);
    *(uint2*)(xb + ia) = *(const uint2*)ra;
    *(uint2*)(xb + ib) = *(const uint2*)rb;

    int p0 = __builtin_amdgcn_cvt_pk_fp8_f32(a.x, a.y, 0, false);
    p0     = __builtin_amdgcn_cvt_pk_fp8_f32(a.z, a.w, p0, true);
    int p1 = __builtin_amdgcn_cvt_pk_fp8_f32(b.x, b.y, 0, false);
    p1     = __builtin_amdgcn_cvt_pk_fp8_f32(b.z, b.w, p1, true);
    *(int*)(x8 + ia) = p0;
    *(int*)(x8 + ib) = p1;
}

// ---------------------------------------------------------------------------
// Kernel 2 (gemm_sym): E = exp(mask(x x^T)), triangular 528-block grid of
// 128^2 tiles, 256 threads / 4 waves (2x2), 64x64 wave tile, fp8 K=128 via
// mfma_scale_f32_16x16x128_f8f6f4 (e8m0 2^-6 scales -> exact 1/4096).
// REVERTED to the R7/R9-verified 2-phase prefetch dbuf (64 KB LDS =
// 2 blocks/CU).  R10's tri-buffer depth-2 counted-vmcnt (96 KB -> 1
// block/CU) cost +20 us: the occupancy loss removed the cross-block wave
// overlap (m114) that was covering the drain latency.
// LDS swizzle: k-block c of row r at slot sigma(c)^(r&7),
// sigma(c) = (c&1)*4 + (c>>1); fragment reads hit slots q^l7 / (4+q)^l7 --
// 0-conflict pattern.  Stager: skb = sigma^-1((t&7)^(srow&7)).
// ---------------------------------------------------------------------------
__global__ __launch_bounds__(256) void gemm_sym(const uint8_t* __restrict__ X8,
                                                unsigned short* __restrict__ E,
                                                float* __restrict__ rowsum) {
    __shared__ __align__(16) uint8_t smem[65536];  // 2 x (A 16KB + B 16KB)

    const int t    = threadIdx.x;
    const int lane = t & 63;
    const int wave = t >> 6;      // 0..3
    const int wm   = wave >> 1;   // 0..1  (64-row strip)
    const int wn   = wave & 1;    // 0..1  (64-col strip)
    const int l15  = lane & 15;
    const int l7   = lane & 7;
    const int q    = lane >> 4;

    // XCD-chunk swizzle: XCD x owns the contiguous triangle range [66x,66x+65]
    const int b0 = blockIdx.x;
    const int b  = (b0 & 7) * 66 + (b0 >> 3);
    // decode triangular block index: b = I*(I+1)/2 + J, J <= I  (32 rows)
    int I = (int)((sqrtf((float)(8 * b + 1)) - 1.0f) * 0.5f);
    if ((I + 1) * (I + 2) / 2 <= b) ++I;   // fp-safety fixups
    if (I * (I + 1) / 2 > b) --I;
    const int Jb = b - I * (I + 1) / 2;
    const int bm = I * BM;   // row block (>= col block)
    const int bn = Jb * BM;
    const bool diag = (I == Jb);

    floatx4 acc[4][4] = {};

    // staging: slot s=t covers row srow (32 rows/issue), slot t&7 holds
    // global k-block sigma^-1((t&7)^(srow&7))
    const int srow = t >> 3;                    // 0..31 (+32*i)
    const int x_   = (t & 7) ^ (srow & 7);
    const int skb  = ((x_ & 3) << 1) | (x_ >> 2);   // sigma^-1
    const uint8_t* Ag = X8 + (long)(bm + srow) * N + skb * 16;
    const uint8_t* Bg = X8 + (long)(bn + srow) * N + skb * 16;

    // prologue: stage tile 0 into buf 0
#pragma unroll
    for (int i = 0; i < 4; ++i) {
        gld_lds16(Ag + (long)i * 32 * N, smem + t * 16 + i * 4096);
        gld_lds16(Bg + (long)i * 32 * N, smem + 16384 + t * 16 + i * 4096);
    }
    __syncthreads();

    int cur = 0;
    for (int k0 = 0; k0 < N; k0 += SK) {
        // prefetch tile t+1 into buf cur^1 (lands during compute below)
        if (k0 + SK < N) {
            uint8_t* An = smem + (cur ^ 1) * 32768 + t * 16;
#pragma unroll
            for (int i = 0; i < 4; ++i) {
                gld_lds16(Ag + (long)i * 32 * N + k0 + SK, An + i * 4096);
                gld_lds16(Bg + (long)i * 32 * N + k0 + SK, An + 16384 + i * 4096);
            }
        }

        const uint8_t* As = smem + cur * 32768;
        const uint8_t* Bs = As + 16384;
        i32x8 af[4], bfr[4];
#pragma unroll
        for (int i = 0; i < 4; ++i) {
            const int row = wm * 64 + i * 16 + l15;   // row&7 == l7
            i32x4 lo = *(const i32x4*)&As[(row * 8 + (q ^ l7)) * 16];
            i32x4 hi = *(const i32x4*)&As[(row * 8 + ((4 + q) ^ l7)) * 16];
            af[i] = (i32x8){lo.x, lo.y, lo.z, lo.w, hi.x, hi.y, hi.z, hi.w};
        }
#pragma unroll
        for (int j = 0; j < 4; ++j) {
            const int row = wn * 64 + j * 16 + l15;
            i32x4 lo = *(const i32x4*)&Bs[(row * 8 + (q ^ l7)) * 16];
            i32x4 hi = *(const i32x4*)&Bs[(row * 8 + ((4 + q) ^ l7)) * 16];
            bfr[j] = (i32x8){lo.x, lo.y, lo.z, lo.w, hi.x, hi.y, hi.z, hi.w};
        }
#pragma unroll
        for (int i = 0; i < 4; ++i)
#pragma unroll
            for (int j = 0; j < 4; ++j)
                acc[i][j] = __builtin_amdgcn_mfma_scale_f32_16x16x128_f8f6f4(
                    af[i], bfr[j], acc[i][j],
                    0, 0,               // cbsz (A fp8 e4m3), blgp (B fp8)
                    0, 0x79797979,      // A scale: e8m0 121 = 2^-6
                    0, 0x79797979);     // B scale: 2^-6  (product: 1/4096)
        __syncthreads();
        cur ^= 1;
    }

    // ---- epilogue: C/D layout col=lane&15, row=(lane>>4)*4+reg ----
    const int col0 = bn + wn * 64 + l15;
    const int row0 = bm + wm * 64 + q * 4;

#pragma unroll
    for (int i = 0; i < 4; ++i) {
#pragma unroll
        for (int r = 0; r < 4; ++r) {
            const int row = row0 + i * 16 + r;
            float rs = 0.f;
#pragma unroll
            for (int j = 0; j < 4; ++j) {
                const int col = col0 + j * 16;
                // no max-subtraction: sims ~ +-0.3, exp safe; shift cancels.
                float e = (row == col) ? 0.f : __expf(acc[i][j][r]);
                acc[i][j][r] = e;
                rs += e;
                E[(long)row * N + col] = f2bf(e);
            }
#pragma unroll
            for (int off = 1; off < 16; off <<= 1) rs += __shfl_xor(rs, off);
            if (l15 == 0) atomicAdd(rowsum + row, rs);
        }
    }

    if (!diag) {
        // column sums -> row sums of the mirror tile
#pragma unroll
        for (int j = 0; j < 4; ++j) {
            float cs = 0.f;
#pragma unroll
            for (int i = 0; i < 4; ++i)
#pragma unroll
                for (int r = 0; r < 4; ++r) cs += acc[i][j][r];
            cs += __shfl_xor(cs, 16);
            cs += __shfl_xor(cs, 32);
            if (q == 0) atomicAdd(rowsum + bn + wn * 64 + j * 16 + l15, cs);
        }

        // per-wave 64x64 transpose through swizzled LDS (8 KB/wave; the
        // K-loop's final syncthreads drained all staging, and the guarded
        // last prefetch means no loads are still in flight)
        unsigned short* tb = (unsigned short*)smem + wave * 4096;
        __syncthreads();
#pragma unroll
        for (int i = 0; i < 4; ++i) {
            const int lr0 = i * 16 + q * 4;
            const int blk = lr0 >> 3;
            const int half = (lr0 >> 2) & 1;
#pragma unroll
            for (int j = 0; j < 4; ++j) {
                const int lc = j * 16 + l15;
                union { unsigned short u[4]; uint2 v2; } pk;
#pragma unroll
                for (int r = 0; r < 4; ++r) pk.u[r] = f2bf(acc[i][j][r]);
                *(uint2*)&tb[lc * 64 + 8 * (blk ^ (lc & 7)) + 4 * half] = pk.v2;
            }
        }
        __syncthreads();

        const int gr0 = lane >> 3;
        const int cb  = lane & 7;
#pragma unroll
        for (int p = 0; p < 8; ++p) {
            const int gr = p * 8 + gr0;
            uint4 v = *(const uint4*)&tb[gr * 64 + 8 * (cb ^ (gr & 7))];
            *(uint4*)&E[(long)(bn + wn * 64 + gr) * N + bm + wm * 64 + cb * 8] = v;
        }
    }
}

// ---------------------------------------------------------------------------
// Kernel 3 (gemm_pv): out = (E/rowsum) x^T.  256^2 8-phase schedule
// (T3+T4 counted-vmcnt + T5 setprio) -- R7/R9-verified (118.5-119.0 us /
// ~1160 TF / MfmaUtil 49% / 0 conflicts).  UNCHANGED.
// ---------------------------------------------------------------------------
#define PV_STAGE_A(buf, h, k0) do { \
    const bf16* s_ = Asrc + (h) * 128 * (long)N + (k0); \
    bf16* d_ = dstl + (buf) * 16384 + (h) * 8192; \
    gld_lds16(s_, d_); \
    gld_lds16(s_ + 64 * (long)N, d_ + 4096); } while (0)

#define PV_STAGE_B(buf, h, k0) do { \
    const bf16* s_ = Bsrc + (h) * 128 * (long)N + (k0); \
    bf16* d_ = dstl + 32768 + (buf) * 16384 + (h) * 8192; \
    gld_lds16(s_, d_); \
    gld_lds16(s_ + 64 * (long)N, d_ + 4096); } while (0)

#define PV_LDA(buf, mi) do { \
    const bf16* b_ = lds + (buf) * 16384; \
    _Pragma("unroll") for (int f_ = 0; f_ < 4; ++f_) { \
      const int r_ = wm * 128 + (mi) * 64 + f_ * 16 + l15; \
      ar[f_][0] = *(const bfrag*)&b_[(r_ * 8 + (q ^ l7)) * 8]; \
      ar[f_][1] = *(const bfrag*)&b_[(r_ * 8 + ((4 + q) ^ l7)) * 8]; } } while (0)

#define PV_LDB(buf, nj) do { \
    const bf16* b_ = lds + 32768 + (buf) * 16384; \
    _Pragma("unroll") for (int g_ = 0; g_ < 2; ++g_) { \
      const int r_ = wn * 64 + (nj) * 32 + g_ * 16 + l15; \
      br[nj][g_][0] = *(const bfrag*)&b_[(r_ * 8 + (q ^ l7)) * 8]; \
      br[nj][g_][1] = *(const bfrag*)&b_[(r_ * 8 + ((4 + q) ^ l7)) * 8]; } } while (0)

#define PV_MM(mi, nj) do { \
    __builtin_amdgcn_s_setprio(1); \
    _Pragma("unroll") for (int f_ = 0; f_ < 4; ++f_) \
    _Pragma("unroll") for (int g_ = 0; g_ < 2; ++g_) \
    _Pragma("unroll") for (int k_ = 0; k_ < 2; ++k_) \
      acc[(mi)*4+f_][(nj)*2+g_] = __builtin_amdgcn_mfma_f32_16x16x32_bf16( \
          ar[f_][k_], br[nj][g_][k_], acc[(mi)*4+f_][(nj)*2+g_], 0, 0, 0); \
    __builtin_amdgcn_s_setprio(0); } while (0)

__global__ __launch_bounds__(512, 2) void gemm_pv(const bf16* __restrict__ A,
                                                  const bf16* __restrict__ B,
                                                  float* __restrict__ C,
                                                  const float* __restrict__ rowsum) {
    __shared__ __align__(16) bf16 lds[4 * 16384];  // 128 KiB: A0 A1 B0 B1

    const int t    = threadIdx.x;
    const int lane = t & 63;
    const int wm   = (t >> 6) >> 2;  // 0..1 (128-row strip)
    const int wn   = (t >> 6) & 3;   // 0..3 (64-col strip)
    const int l15  = lane & 15;
    const int l7   = lane & 7;
    const int q    = lane >> 4;

    // bijective XCD swizzle (256 blocks % 8 XCDs == 0)
    const int swz = (blockIdx.x & 7) * 32 + (blockIdx.x >> 3);
    const int bm  = (swz >> 4) * PM;
    const int bn  = (swz & 15) * PN;

    const int srow = t >> 3;
    const int skb  = (t & 7) ^ (srow & 7);
    const bf16* Asrc = A + (long)(bm + srow) * N + skb * 8;
    const bf16* Bsrc = B + (long)(bn + srow) * N + skb * 8;
    bf16* dstl = lds + t * 8;

    floatx4 acc[8][4] = {};
    bfrag ar[4][2], br[2][2][2];

    // prologue: B(0),A(0) -> buf0; B(1) -> buf1.  A(1) staged in ph1/2.
    PV_STAGE_B(0, 0, 0); PV_STAGE_B(0, 1, 0);
    PV_STAGE_A(0, 0, 0); PV_STAGE_A(0, 1, 0);
    PV_STAGE_B(1, 0, PK); PV_STAGE_B(1, 1, PK);
    PV_VM4();
    PV_BAR();

    for (int i = 0; i < 32; ++i) {
        const int ka1 = ((2 * i + 1) * PK) & (N - 1);
        const int kb2 = ((2 * i + 2) * PK) & (N - 1);
        const int kb3 = ((2 * i + 3) * PK) & (N - 1);
        PV_LDA(0, 0); PV_LDB(0, 0); PV_STAGE_A(1, 0, ka1);
        PV_BAR(); PV_LGKM0();
        PV_MM(0, 0);
        PV_BAR();
        PV_LDB(0, 1); PV_STAGE_A(1, 1, ka1);
        PV_BAR(); PV_LGKM0();
        PV_MM(0, 1);
        PV_BAR();
        PV_LDA(0, 1); PV_STAGE_B(0, 0, kb2);
        PV_BAR(); PV_LGKM0();
        PV_MM(1, 1);
        PV_BAR();
        PV_STAGE_B(0, 1, kb2);
        PV_BAR();
        PV_MM(1, 0);
        PV_VM4(); PV_BAR();
        PV_LDA(1, 0); PV_LDB(1, 0); PV_STAGE_A(0, 0, kb2);
        PV_BAR(); PV_LGKM0();
        PV_MM(0, 0);
        PV_BAR();
        PV_LDB(1, 1); PV_STAGE_A(0, 1, kb2);
        PV_BAR(); PV_LGKM0();
        PV_MM(0, 1);
        PV_BAR();
        PV_LDA(1, 1); PV_STAGE_B(1, 0, kb3);
        PV_BAR(); PV_LGKM0();
        PV_MM(1, 1);
        PV_BAR();
        PV_STAGE_B(1, 1, kb3);
        PV_BAR();
        PV_MM(1, 0);
        PV_VM4(); PV_BAR();
    }

    // epilogue: C/D layout col=lane&15, row=q*4+reg; fuse 1/rowsum
    const int rowbase = bm + wm * 128 + q * 4;
    const int colbase = bn + wn * 64 + l15;
#pragma unroll
    for (int f = 0; f < 8; ++f) {
#pragma unroll
        for (int r = 0; r < 4; ++r) {
            const int row = rowbase + f * 16 + r;
            const float inv = 1.0f / rowsum[row];
#pragma unroll
            for (int g = 0; g < 4; ++g)
                C[(long)row * N + colbase + g * 16] = acc[f][g][r] * inv;
        }
    }
}

// ---------------------------------------------------------------------------
extern "C" void kernel_launch(void* const* d_in, const int* in_sizes, int n_in,
                              void* d_out, int out_size, void* d_ws, size_t ws_size,
                              hipStream_t stream) {
    const float* in = (const float*)d_in[0];
    float* out = (float*)d_out;

    // ws layout: [rowsum 16KB] [xb 32MB bf16] [E 32MB bf16].
    // x8 (16MB fp8) lives in d_out's first 16MB -- dead until gemm_pv's
    // final write, which happens after gemm_sym has consumed x8.
    float* rowsum = (float*)d_ws;
    bf16* xb = (bf16*)((char*)d_ws + 16384);
    unsigned short* E = (unsigned short*)((char*)d_ws + 16384 + (size_t)N * N * sizeof(bf16));
    uint8_t* x8 = (uint8_t*)d_out;

    hipMemsetAsync(rowsum, 0, 16384, stream);   // stream-ordered zeroing

    cvt_scale<<<(N * (long)N) / (256 * 8), 256, 0, stream>>>(
        in, (unsigned short*)xb, x8);

    // E = exp(mask(x x^T)) via 528 triangular 128^2 fp8 tiles
    // (2-phase prefetch dbuf + XCD-chunk swizzle -- R7/R9-verified)
    gemm_sym<<<528, 256, 0, stream>>>(x8, E, rowsum);
    // out = (E / rowsum) x^T  -- 256^2 8-phase, 256 blocks (1/CU)
    gemm_pv<<<256, 512, 0, stream>>>((const bf16*)E, xb, out, rowsum);
}